// Round 8
// baseline (292.891 us; speedup 1.0000x reference)
//
#include <hip/hip_runtime.h>
#include <hip/hip_bf16.h>
#include <stdint.h>

// B=2, T=2048, E=1024, H=16, D=64 ; M = B*T = 4096
// Inputs fp32, output fp32 (verified by R7 probe: code=5, Q-region readback).
// bf16 MFMA (16x16x32), fp32 accumulate. Scale = 1/sqrt(E) = 1/32.
// R7 root cause fixed: GEMM LDS staging used stride-16 indexing with 8-element
// short8 stores, leaving As/Bs cols 8-15,24-31 stale. Staging now fully covers.
// Workspace: Qb 8 + Kb 8 + Vb 8 + Vt 8 + Wt 2 = 34 MB (Ob aliases Vb).

typedef __attribute__((ext_vector_type(8))) short short8;    // 8 bf16 (4 VGPRs)
typedef __attribute__((ext_vector_type(4))) short short4v;   // 4 bf16 (8B)
typedef __attribute__((ext_vector_type(4))) float f32x4;     // MFMA C/D

#define MFMA16(a, b, c) __builtin_amdgcn_mfma_f32_16x16x32_bf16((a), (b), (c), 0, 0, 0)

static __device__ __forceinline__ unsigned short f2bf(float f) {
    union { float f; unsigned int u; } v; v.f = f;
    unsigned int r = v.u + 0x7fffu + ((v.u >> 16) & 1u);   // RNE
    return (unsigned short)(r >> 16);
}

// --------------------------------- transpose+convert W [K,N] fp32 -> Wt [N,K] bf16
__global__ __launch_bounds__(256) void k_transpose_w(const float* __restrict__ W,
                                                     unsigned short* __restrict__ Wt) {
    __shared__ float tw[64][68];                   // 272B row stride (16B aligned)
    const int k0 = blockIdx.x * 64, n0 = blockIdx.y * 64;
    const int tid = threadIdx.x;
#pragma unroll
    for (int r = 0; r < 4; ++r) {
        int i = tid + r * 256;                     // 1024 float4 loads
        int row = i >> 4, c4 = (i & 15) * 4;
        float4 v = *(const float4*)(W + (size_t)(k0 + row) * 1024 + n0 + c4);
        *(float4*)(&tw[row][c4]) = v;
    }
    __syncthreads();
#pragma unroll
    for (int r = 0; r < 2; ++r) {
        int i = tid + r * 256;                     // 512 16B stores
        int nrow = i >> 3, kc = (i & 7) * 8;
        short8 o;
#pragma unroll
        for (int j = 0; j < 8; ++j) o[j] = (short)f2bf(tw[kc + j][nrow]);
        *(short8*)(Wt + (size_t)(n0 + nrow) * 1024 + k0 + kc) = o;
    }
}

// ---------------------------------------------------------------- GEMM
// C[M=4096, N=1024] = A[M,K=1024] @ Wt^T + bias(fp32) ; BM=128, BN=64, BK=32
// AF32=1: A fp32 (converted during staging; QKV gemms read x directly).
// AF32=0: A bf16 (Ob). FOUT32=1: write fp32 C (final). Else bf16 C.
template <int AF32, int FOUT32>
__global__ __launch_bounds__(256) void k_gemm(const void* __restrict__ Ain,
                                              const unsigned short* __restrict__ Bt,
                                              const float* __restrict__ bias,
                                              void* __restrict__ Cout) {
    __shared__ unsigned short As[128][40];         // +8 pad: 2-way LDS (free)
    __shared__ unsigned short Bs[64][40];
    const int tid = threadIdx.x;
    const int w = tid >> 6, lane = tid & 63;
    const int quad = lane >> 4, l16 = lane & 15;
    const int wm = w >> 1, wn = w & 1;             // 2x2 wave grid: 64x32 per wave
    const int m0 = blockIdx.x * 128, n0 = blockIdx.y * 64;

    f32x4 acc[4][2];
#pragma unroll
    for (int mt = 0; mt < 4; ++mt)
#pragma unroll
        for (int nt = 0; nt < 2; ++nt) acc[mt][nt] = (f32x4){0.f, 0.f, 0.f, 0.f};

    for (int k0 = 0; k0 < 1024; k0 += 32) {
        __syncthreads();
        if (AF32) {
            const float* A32 = (const float*)Ain;
#pragma unroll
            for (int r = 0; r < 4; ++r) {          // 128x32 fp32 -> bf16, full cover
                int i = tid + r * 256;             // i in [0,1024)
                int arow = i >> 3, ac4 = (i & 7) * 4;
                float4 v = *(const float4*)(A32 + (size_t)(m0 + arow) * 1024 + k0 + ac4);
                short4v o;
                o[0] = (short)f2bf(v.x); o[1] = (short)f2bf(v.y);
                o[2] = (short)f2bf(v.z); o[3] = (short)f2bf(v.w);
                *(short4v*)(&As[arow][ac4]) = o;
            }
        } else {
            const unsigned short* A16 = (const unsigned short*)Ain;
#pragma unroll
            for (int r = 0; r < 2; ++r) {          // 128x32 bf16, 512 short8 stores
                int i = tid + r * 256;             // i in [0,512)
                int arow = i >> 2, ac8 = (i & 3) * 8;
                *(short8*)(&As[arow][ac8]) =
                    *(const short8*)(A16 + (size_t)(m0 + arow) * 1024 + k0 + ac8);
            }
        }
        {                                          // B 64x32: 256 short8 stores
            int brow = tid >> 2, bc8 = (tid & 3) * 8;
            *(short8*)(&Bs[brow][bc8]) =
                *(const short8*)(Bt + (size_t)(n0 + brow) * 1024 + k0 + bc8);
        }
        __syncthreads();
        short8 af[4], bf[2];
#pragma unroll
        for (int mt = 0; mt < 4; ++mt)
            af[mt] = *(const short8*)(&As[wm * 64 + mt * 16 + l16][quad * 8]);
#pragma unroll
        for (int nt = 0; nt < 2; ++nt)
            bf[nt] = *(const short8*)(&Bs[wn * 32 + nt * 16 + l16][quad * 8]);
#pragma unroll
        for (int mt = 0; mt < 4; ++mt)
#pragma unroll
            for (int nt = 0; nt < 2; ++nt)
                acc[mt][nt] = MFMA16(af[mt], bf[nt], acc[mt][nt]);
    }
    // epilogue: C/D layout col=lane&15, row=quad*4+reg
#pragma unroll
    for (int nt = 0; nt < 2; ++nt) {
        int col = n0 + wn * 32 + nt * 16 + l16;
        float bv_ = bias[col];
#pragma unroll
        for (int mt = 0; mt < 4; ++mt) {
#pragma unroll
            for (int r = 0; r < 4; ++r) {
                int row = m0 + wm * 64 + mt * 16 + quad * 4 + r;
                float v = acc[mt][nt][r] + bv_;
                if (FOUT32)
                    ((float*)Cout)[(size_t)row * 1024 + col] = v;
                else
                    ((unsigned short*)Cout)[(size_t)row * 1024 + col] = f2bf(v);
            }
        }
    }
}

// ------------------------------------------- V [b*T+t, h*64+d] -> Vt [(b*H+h)*64+d, t]
__global__ __launch_bounds__(256) void k_transpose_v(const unsigned short* __restrict__ Vb,
                                                     unsigned short* __restrict__ Vt) {
    __shared__ unsigned short vt[64][72];
    const int t0 = blockIdx.x * 64;
    const int bh = blockIdx.y, b = bh >> 4, h = bh & 15;
    const int tid = threadIdx.x;
#pragma unroll
    for (int r = 0; r < 2; ++r) {
        int i = tid + r * 256;                     // 512 16B loads
        int trow = i >> 3, c8 = (i & 7) * 8;
        *(short8*)(&vt[trow][c8]) =
            *(const short8*)(Vb + (size_t)(b * 2048 + t0 + trow) * 1024 + h * 64 + c8);
    }
    __syncthreads();
#pragma unroll
    for (int r = 0; r < 2; ++r) {
        int i = tid + r * 256;
        int drow = i >> 3, c8 = (i & 7) * 8;
        short8 o;
#pragma unroll
        for (int j = 0; j < 8; ++j) o[j] = (short)vt[c8 + j][drow];
        *(short8*)(Vt + (size_t)(bh * 64 + drow) * 2048 + t0 + c8) = o;
    }
}

// ---------------------------------------------------------------- flash attention
// grid (16, 32): x = load-balanced q-tile pair (p, 31-p), y = (b,h)
__global__ __launch_bounds__(256) void k_attn(const unsigned short* __restrict__ Qb,
                                              const unsigned short* __restrict__ Kb,
                                              const unsigned short* __restrict__ Vt,
                                              unsigned short* __restrict__ Ob) {
    __shared__ unsigned short Ks[64][72];          // [kk][d]
    __shared__ unsigned short Vs[64][72];          // [d][kk]  (from Vt)
    __shared__ unsigned short Ps[4][16][72];       // per-wave P relayout buffer
    const int tid = threadIdx.x;
    const int w = tid >> 6, lane = tid & 63;
    const int quad = lane >> 4, l16 = lane & 15;
    const int bh = blockIdx.y, b = bh >> 4, h = bh & 15;
    const float scale = 0.03125f;                  // 1/sqrt(1024)

    for (int half = 0; half < 2; ++half) {
        const int qb = (half == 0) ? (int)blockIdx.x : 31 - (int)blockIdx.x;
        const int q0 = qb * 64;
        // Q fragments: A[m=lane&15][k=quad*8+j], k-steps d0=0,32
        short8 qf[2];
        {
            size_t qrow = (size_t)(b * 2048 + q0 + w * 16 + l16) * 1024 + h * 64;
            qf[0] = *(const short8*)(Qb + qrow + quad * 8);
            qf[1] = *(const short8*)(Qb + qrow + 32 + quad * 8);
        }
        float m_[4], l_[4];
        f32x4 o[4];
#pragma unroll
        for (int r = 0; r < 4; ++r) { m_[r] = -1e30f; l_[r] = 0.f; }
#pragma unroll
        for (int dt = 0; dt < 4; ++dt) o[dt] = (f32x4){0.f, 0.f, 0.f, 0.f};

        for (int kt = 0; kt <= qb; ++kt) {
            __syncthreads();                       // protect Ks/Vs from prev iter readers
#pragma unroll
            for (int r = 0; r < 2; ++r) {
                int i = tid + r * 256;
                int row = i >> 3, c8 = (i & 7) * 8;
                *(short8*)(&Ks[row][c8]) = *(const short8*)(
                    Kb + (size_t)(b * 2048 + kt * 64 + row) * 1024 + h * 64 + c8);
                *(short8*)(&Vs[row][c8]) = *(const short8*)(
                    Vt + (size_t)(bh * 64 + row) * 2048 + kt * 64 + c8);
            }
            __syncthreads();

            // S = Q K^T for this wave's 16 q-rows x 64 kk
            f32x4 s[4];
#pragma unroll
            for (int kkt = 0; kkt < 4; ++kkt) {
                s[kkt] = (f32x4){0.f, 0.f, 0.f, 0.f};
                short8 kf0 = *(const short8*)(&Ks[kkt * 16 + l16][quad * 8]);
                short8 kf1 = *(const short8*)(&Ks[kkt * 16 + l16][32 + quad * 8]);
                s[kkt] = MFMA16(qf[0], kf0, s[kkt]);
                s[kkt] = MFMA16(qf[1], kf1, s[kkt]);
            }

            // scale + causal mask + online softmax (rows = q0+w*16+quad*4+r)
            const int rowg = q0 + w * 16 + quad * 4;
            float mx[4];
#pragma unroll
            for (int r = 0; r < 4; ++r) mx[r] = -1e30f;
#pragma unroll
            for (int kkt = 0; kkt < 4; ++kkt) {
                int colg = kt * 64 + kkt * 16 + l16;
#pragma unroll
                for (int r = 0; r < 4; ++r) {
                    float v = s[kkt][r] * scale;
                    v = (kt == qb && colg > rowg + r) ? -1e30f : v;
                    s[kkt][r] = v;
                    mx[r] = fmaxf(mx[r], v);
                }
            }
#pragma unroll
            for (int off = 8; off >= 1; off >>= 1)
#pragma unroll
                for (int r = 0; r < 4; ++r)
                    mx[r] = fmaxf(mx[r], __shfl_xor(mx[r], off, 64));
            float al[4], sum[4];
#pragma unroll
            for (int r = 0; r < 4; ++r) {
                float mn = fmaxf(m_[r], mx[r]);
                al[r] = __expf(m_[r] - mn);
                m_[r] = mn;
                sum[r] = 0.f;
            }
#pragma unroll
            for (int kkt = 0; kkt < 4; ++kkt)
#pragma unroll
                for (int r = 0; r < 4; ++r) {
                    float p = __expf(s[kkt][r] - m_[r]);
                    s[kkt][r] = p;
                    sum[r] += p;
                }
#pragma unroll
            for (int off = 8; off >= 1; off >>= 1)
#pragma unroll
                for (int r = 0; r < 4; ++r) sum[r] += __shfl_xor(sum[r], off, 64);
#pragma unroll
            for (int r = 0; r < 4; ++r) l_[r] = l_[r] * al[r] + sum[r];
#pragma unroll
            for (int dt = 0; dt < 4; ++dt)
#pragma unroll
                for (int r = 0; r < 4; ++r) o[dt][r] *= al[r];

            // P: C-layout regs -> LDS -> A-layout frags (barrier = full fence)
#pragma unroll
            for (int kkt = 0; kkt < 4; ++kkt)
#pragma unroll
                for (int r = 0; r < 4; ++r)
                    Ps[w][quad * 4 + r][kkt * 16 + l16] = f2bf(s[kkt][r]);
            __syncthreads();                       // uniform: qb is block-uniform
#pragma unroll
            for (int kks = 0; kks < 2; ++kks) {
                short8 pf = *(const short8*)(&Ps[w][l16][kks * 32 + quad * 8]);
#pragma unroll
                for (int dt = 0; dt < 4; ++dt) {
                    short8 vf = *(const short8*)(&Vs[dt * 16 + l16][kks * 32 + quad * 8]);
                    o[dt] = MFMA16(pf, vf, o[dt]);
                }
            }
        }

        // epilogue: O row = q0+w*16+quad*4+r, col = h*64+dt*16+l16
        const int orow = b * 2048 + q0 + w * 16 + quad * 4;
#pragma unroll
        for (int r = 0; r < 4; ++r) {
            float inv = 1.0f / l_[r];
#pragma unroll
            for (int dt = 0; dt < 4; ++dt)
                Ob[(size_t)(orow + r) * 1024 + h * 64 + dt * 16 + l16] =
                    f2bf(o[dt][r] * inv);
        }
    }
}

// ---------------------------------------------------------------- launch
extern "C" void kernel_launch(void* const* d_in, const int* in_sizes, int n_in,
                              void* d_out, int out_size, void* d_ws, size_t ws_size,
                              hipStream_t stream) {
    const float* x  = (const float*)d_in[0];
    const float* Wq = (const float*)d_in[1];
    const float* bq = (const float*)d_in[2];
    const float* Wk = (const float*)d_in[3];
    const float* bk = (const float*)d_in[4];
    const float* Wv = (const float*)d_in[5];
    const float* bv = (const float*)d_in[6];
    const float* Wo = (const float*)d_in[7];
    const float* bo = (const float*)d_in[8];
    float* out = (float*)d_out;                    // fp32 output (probe-verified)

    const size_t M4 = 4194304, M1 = 1048576;
    const size_t NEED = (4 * M4 + M1) * 2;         // 34 MB
    if (ws_size < NEED) return;
    unsigned short* ws = (unsigned short*)d_ws;
    unsigned short* Qb = ws;                       // 8 MB
    unsigned short* Kb = Qb + M4;                  // 8 MB
    unsigned short* Vb = Kb + M4;                  // 8 MB (Ob aliases after transpose)
    unsigned short* Ob = Vb;
    unsigned short* Vt = Vb + M4;                  // 8 MB, [(b*16+h)*64+d][t]
    unsigned short* Wt = Vt + M4;                  // 2 MB, reused per weight

    dim3 gw(16, 16), gg(32, 16);
    k_transpose_w<<<gw, 256, 0, stream>>>(Wq, Wt);
    k_gemm<1, 0><<<gg, 256, 0, stream>>>(x, Wt, bq, Qb);
    k_transpose_w<<<gw, 256, 0, stream>>>(Wk, Wt);
    k_gemm<1, 0><<<gg, 256, 0, stream>>>(x, Wt, bk, Kb);
    k_transpose_w<<<gw, 256, 0, stream>>>(Wv, Wt);
    k_gemm<1, 0><<<gg, 256, 0, stream>>>(x, Wt, bv, Vb);
    k_transpose_v<<<dim3(32, 32), 256, 0, stream>>>(Vb, Vt);
    k_attn<<<dim3(16, 32), 256, 0, stream>>>(Qb, Kb, Vt, Ob);
    k_transpose_w<<<gw, 256, 0, stream>>>(Wo, Wt);
    k_gemm<0, 1><<<gg, 256, 0, stream>>>(Ob, Wt, bo, out);
}

// Round 9
// 246.653 us; speedup vs baseline: 1.1875x; 1.1875x over previous
//
#include <hip/hip_runtime.h>
#include <hip/hip_bf16.h>
#include <stdint.h>

// B=2, T=2048, E=1024, H=16, D=64 ; M = B*T = 4096
// Inputs fp32, output fp32. bf16 MFMA 16x16x32, fp32 accumulate. Scale 1/32.
// R9: m97-style GEMM (128x128 tile, global_load_lds 16B, unpadded LDS),
// fused QKV GEMM (N=3072) with in-epilogue V transpose, attn occupancy 2x
// (1024 blocks) + XCD-aware bh grouping. Qb/Kb live in d_out as scratch.
// ws: xb/Ob 8 + Vt 8 + WtQKV 6 + Wto 2 = 24 MB.

typedef __attribute__((ext_vector_type(8))) short short8;    // 8 bf16
typedef __attribute__((ext_vector_type(4))) short short4v;   // 4 bf16
typedef __attribute__((ext_vector_type(4))) float f32x4;

#define MFMA16(a, b, c) __builtin_amdgcn_mfma_f32_16x16x32_bf16((a), (b), (c), 0, 0, 0)

static __device__ __forceinline__ unsigned short f2bf(float f) {
    union { float f; unsigned int u; } v; v.f = f;
    unsigned int r = v.u + 0x7fffu + ((v.u >> 16) & 1u);   // RNE
    return (unsigned short)(r >> 16);
}
// async global->LDS, 16B per lane; LDS dest = wave-uniform base + lane*16
static __device__ __forceinline__ void gload16(const unsigned short* g,
                                               unsigned short* l) {
    __builtin_amdgcn_global_load_lds(
        (const __attribute__((address_space(1))) void*)g,
        (__attribute__((address_space(3))) void*)l, 16, 0, 0);
}

// ---------------------------------------------------------------- convert x -> bf16
__global__ __launch_bounds__(256) void k_convert_x(const float* __restrict__ x,
                                                   unsigned short* __restrict__ xb) {
    int i = blockIdx.x * 256 + threadIdx.x;        // 8 elements/thread
    const float4* p = (const float4*)(x + (size_t)i * 8);
    float4 a = p[0], b = p[1];
    short8 o;
    o[0] = (short)f2bf(a.x); o[1] = (short)f2bf(a.y);
    o[2] = (short)f2bf(a.z); o[3] = (short)f2bf(a.w);
    o[4] = (short)f2bf(b.x); o[5] = (short)f2bf(b.y);
    o[6] = (short)f2bf(b.z); o[7] = (short)f2bf(b.w);
    ((short8*)xb)[i] = o;
}

// ---------------- transpose+convert all 4 weights: W [K,N] fp32 -> Wt [N,K] bf16
__global__ __launch_bounds__(256) void k_transpose_w4(
        const float* __restrict__ W0, const float* __restrict__ W1,
        const float* __restrict__ W2, const float* __restrict__ W3,
        unsigned short* __restrict__ T0, unsigned short* __restrict__ T1,
        unsigned short* __restrict__ T2, unsigned short* __restrict__ T3) {
    const float* W = (blockIdx.z == 0) ? W0 : (blockIdx.z == 1) ? W1
                     : (blockIdx.z == 2) ? W2 : W3;
    unsigned short* Wt = (blockIdx.z == 0) ? T0 : (blockIdx.z == 1) ? T1
                         : (blockIdx.z == 2) ? T2 : T3;
    __shared__ float tw[64][68];
    const int k0 = blockIdx.x * 64, n0 = blockIdx.y * 64;
    const int tid = threadIdx.x;
#pragma unroll
    for (int r = 0; r < 4; ++r) {
        int i = tid + r * 256;
        int row = i >> 4, c4 = (i & 15) * 4;
        float4 v = *(const float4*)(W + (size_t)(k0 + row) * 1024 + n0 + c4);
        *(float4*)(&tw[row][c4]) = v;
    }
    __syncthreads();
#pragma unroll
    for (int r = 0; r < 2; ++r) {
        int i = tid + r * 256;
        int nrow = i >> 3, kc = (i & 7) * 8;
        short8 o;
#pragma unroll
        for (int j = 0; j < 8; ++j) o[j] = (short)f2bf(tw[kc + j][nrow]);
        *(short8*)(Wt + (size_t)(n0 + nrow) * 1024 + k0 + kc) = o;
    }
}

// ---------------------------------------------------------------- GEMM (m97 style)
// C[M=4096, N] = A[M,1024](bf16) @ Bt[N,1024]^T + bias ; 128x128 tile, BK=32.
// MODE 0 (QKV, N=3072): n0<1024 -> Qb ; <2048 -> Kb ; else V transposed into
// Vt[((b*16+h)*64+d)*2048+t]. MODE 1 (O, N=1024): fp32 out + bias.
template <int MODE>
__global__ __launch_bounds__(256) void k_gemm2(const unsigned short* __restrict__ A,
                                               const unsigned short* __restrict__ Bt,
                                               const float* __restrict__ bq,
                                               const float* __restrict__ bk,
                                               const float* __restrict__ bv,
                                               unsigned short* __restrict__ Qb,
                                               unsigned short* __restrict__ Kb,
                                               unsigned short* __restrict__ Vt,
                                               float* __restrict__ Co) {
    __shared__ unsigned short As[128 * 32];        // unpadded: global_load_lds dest
    __shared__ unsigned short Bs[128 * 32];
    const int tid = threadIdx.x;
    const int w = tid >> 6, lane = tid & 63;
    const int quad = lane >> 4, l16 = lane & 15;
    const int wm = w >> 1, wn = w & 1;             // 2x2 waves, 64x64 out each
    const int m0 = blockIdx.x * 128, n0 = blockIdx.y * 128;
    const int lrow = lane >> 2, lch = (lane & 3) * 8;

    const unsigned short* ga = A + (size_t)(m0 + w * 32 + lrow) * 1024 + lch;
    const unsigned short* gb = Bt + (size_t)(n0 + w * 32 + lrow) * 1024 + lch;
    unsigned short* la0 = &As[(w * 32) * 32];
    unsigned short* la1 = &As[(w * 32 + 16) * 32];
    unsigned short* lb0 = &Bs[(w * 32) * 32];
    unsigned short* lb1 = &Bs[(w * 32 + 16) * 32];

    f32x4 acc[4][4];
#pragma unroll
    for (int mt = 0; mt < 4; ++mt)
#pragma unroll
        for (int nt = 0; nt < 4; ++nt) acc[mt][nt] = (f32x4){0.f, 0.f, 0.f, 0.f};

    for (int k0 = 0; k0 < 1024; k0 += 32) {
        __syncthreads();                           // prev readers done
        gload16(ga + k0, la0);
        gload16(ga + 16 * 1024 + k0, la1);
        gload16(gb + k0, lb0);
        gload16(gb + 16 * 1024 + k0, lb1);
        __syncthreads();                           // vmcnt(0) drain + barrier
        short8 af[4], bf[4];
#pragma unroll
        for (int mt = 0; mt < 4; ++mt)
            af[mt] = *(const short8*)(&As[(wm * 64 + mt * 16 + l16) * 32 + quad * 8]);
#pragma unroll
        for (int nt = 0; nt < 4; ++nt)
            bf[nt] = *(const short8*)(&Bs[(wn * 64 + nt * 16 + l16) * 32 + quad * 8]);
#pragma unroll
        for (int mt = 0; mt < 4; ++mt)
#pragma unroll
            for (int nt = 0; nt < 4; ++nt)
                acc[mt][nt] = MFMA16(af[mt], bf[nt], acc[mt][nt]);
    }

    // epilogue: C/D layout col=lane&15, row=quad*4+reg
    if (MODE == 1) {
#pragma unroll
        for (int nt = 0; nt < 4; ++nt) {
            int col = n0 + wn * 64 + nt * 16 + l16;
            float bb = bq[col];
#pragma unroll
            for (int mt = 0; mt < 4; ++mt) {
                int row = m0 + wm * 64 + mt * 16 + quad * 4;
#pragma unroll
                for (int r = 0; r < 4; ++r)
                    Co[(size_t)(row + r) * 1024 + col] = acc[mt][nt][r] + bb;
            }
        }
    } else if (n0 < 2048) {                        // Q or K: bf16 row-major
        unsigned short* C = (n0 < 1024) ? Qb : Kb;
        const float* bias = (n0 < 1024) ? bq : bk;
        int cb = (n0 < 1024) ? n0 : (n0 - 1024);
#pragma unroll
        for (int nt = 0; nt < 4; ++nt) {
            int col = cb + wn * 64 + nt * 16 + l16;
            float bb = bias[col];
#pragma unroll
            for (int mt = 0; mt < 4; ++mt) {
                int row = m0 + wm * 64 + mt * 16 + quad * 4;
#pragma unroll
                for (int r = 0; r < 4; ++r)
                    C[(size_t)(row + r) * 1024 + col] = f2bf(acc[mt][nt][r] + bb);
            }
        }
    } else {                                       // V: transposed per-head store
#pragma unroll
        for (int nt = 0; nt < 4; ++nt) {
            int vcol = (n0 - 2048) + wn * 64 + nt * 16 + l16;   // h*64+d
            float bb = bv[vcol];
#pragma unroll
            for (int mt = 0; mt < 4; ++mt) {
                int row = m0 + wm * 64 + mt * 16 + quad * 4;    // b*2048+t, t%4==0
                int b = row >> 11, t = row & 2047;
                short4v o;
#pragma unroll
                for (int r = 0; r < 4; ++r) o[r] = (short)f2bf(acc[mt][nt][r] + bb);
                *(short4v*)(&Vt[((size_t)(b * 16 + (vcol >> 6)) * 64 + (vcol & 63))
                                    * 2048 + t]) = o;
            }
        }
    }
}

// ---------------------------------------------------------------- flash attention
// grid 1024 1-D: c=id&7 (XCD slot), j=id>>3: bh = c+8*(j&3), qb = j>>2.
// All 32 q-blocks of a bh share id%8 -> same XCD -> K/V L2-resident (2MB/XCD).
__global__ __launch_bounds__(256) void k_attn(const unsigned short* __restrict__ Qb,
                                              const unsigned short* __restrict__ Kb,
                                              const unsigned short* __restrict__ Vt,
                                              unsigned short* __restrict__ Ob) {
    __shared__ unsigned short Ks[64][72];          // [kk][d]
    __shared__ unsigned short Vs[64][72];          // [d][kk]
    __shared__ unsigned short Ps[4][16][72];       // per-wave P relayout
    const int tid = threadIdx.x;
    const int w = tid >> 6, lane = tid & 63;
    const int quad = lane >> 4, l16 = lane & 15;
    const int id = blockIdx.x;
    const int bh = (id & 7) + 8 * ((id >> 3) & 3);
    const int qb = id >> 5;
    const int b = bh >> 4, h = bh & 15;
    const float scale = 0.03125f;                  // 1/sqrt(1024)
    const int q0 = qb * 64;

    short8 qf[2];
    {
        size_t qrow = (size_t)(b * 2048 + q0 + w * 16 + l16) * 1024 + h * 64;
        qf[0] = *(const short8*)(Qb + qrow + quad * 8);
        qf[1] = *(const short8*)(Qb + qrow + 32 + quad * 8);
    }
    float m_[4], l_[4];
    f32x4 o[4];
#pragma unroll
    for (int r = 0; r < 4; ++r) { m_[r] = -1e30f; l_[r] = 0.f; }
#pragma unroll
    for (int dt = 0; dt < 4; ++dt) o[dt] = (f32x4){0.f, 0.f, 0.f, 0.f};

    for (int kt = 0; kt <= qb; ++kt) {
        __syncthreads();
#pragma unroll
        for (int r = 0; r < 2; ++r) {
            int i = tid + r * 256;
            int row = i >> 3, c8 = (i & 7) * 8;
            *(short8*)(&Ks[row][c8]) = *(const short8*)(
                Kb + (size_t)(b * 2048 + kt * 64 + row) * 1024 + h * 64 + c8);
            *(short8*)(&Vs[row][c8]) = *(const short8*)(
                Vt + (size_t)(bh * 64 + row) * 2048 + kt * 64 + c8);
        }
        __syncthreads();

        f32x4 s[4];
#pragma unroll
        for (int kkt = 0; kkt < 4; ++kkt) {
            s[kkt] = (f32x4){0.f, 0.f, 0.f, 0.f};
            short8 kf0 = *(const short8*)(&Ks[kkt * 16 + l16][quad * 8]);
            short8 kf1 = *(const short8*)(&Ks[kkt * 16 + l16][32 + quad * 8]);
            s[kkt] = MFMA16(qf[0], kf0, s[kkt]);
            s[kkt] = MFMA16(qf[1], kf1, s[kkt]);
        }

        const int rowg = q0 + w * 16 + quad * 4;
        float mx[4];
#pragma unroll
        for (int r = 0; r < 4; ++r) mx[r] = -1e30f;
#pragma unroll
        for (int kkt = 0; kkt < 4; ++kkt) {
            int colg = kt * 64 + kkt * 16 + l16;
#pragma unroll
            for (int r = 0; r < 4; ++r) {
                float v = s[kkt][r] * scale;
                v = (kt == qb && colg > rowg + r) ? -1e30f : v;
                s[kkt][r] = v;
                mx[r] = fmaxf(mx[r], v);
            }
        }
#pragma unroll
        for (int off = 8; off >= 1; off >>= 1)
#pragma unroll
            for (int r = 0; r < 4; ++r)
                mx[r] = fmaxf(mx[r], __shfl_xor(mx[r], off, 64));
        float al[4], sum[4];
#pragma unroll
        for (int r = 0; r < 4; ++r) {
            float mn = fmaxf(m_[r], mx[r]);
            al[r] = __expf(m_[r] - mn);
            m_[r] = mn;
            sum[r] = 0.f;
        }
#pragma unroll
        for (int kkt = 0; kkt < 4; ++kkt)
#pragma unroll
            for (int r = 0; r < 4; ++r) {
                float p = __expf(s[kkt][r] - m_[r]);
                s[kkt][r] = p;
                sum[r] += p;
            }
#pragma unroll
        for (int off = 8; off >= 1; off >>= 1)
#pragma unroll
            for (int r = 0; r < 4; ++r) sum[r] += __shfl_xor(sum[r], off, 64);
#pragma unroll
        for (int r = 0; r < 4; ++r) l_[r] = l_[r] * al[r] + sum[r];
#pragma unroll
        for (int dt = 0; dt < 4; ++dt)
#pragma unroll
            for (int r = 0; r < 4; ++r) o[dt][r] *= al[r];

#pragma unroll
        for (int kkt = 0; kkt < 4; ++kkt)
#pragma unroll
            for (int r = 0; r < 4; ++r)
                Ps[w][quad * 4 + r][kkt * 16 + l16] = f2bf(s[kkt][r]);
        __syncthreads();
#pragma unroll
        for (int kks = 0; kks < 2; ++kks) {
            short8 pf = *(const short8*)(&Ps[w][l16][kks * 32 + quad * 8]);
#pragma unroll
            for (int dt = 0; dt < 4; ++dt) {
                short8 vf = *(const short8*)(&Vs[dt * 16 + l16][kks * 32 + quad * 8]);
                o[dt] = MFMA16(pf, vf, o[dt]);
            }
        }
    }

    const int orow = b * 2048 + q0 + w * 16 + quad * 4;
#pragma unroll
    for (int r = 0; r < 4; ++r) {
        float inv = 1.0f / l_[r];
#pragma unroll
        for (int dt = 0; dt < 4; ++dt)
            Ob[(size_t)(orow + r) * 1024 + h * 64 + dt * 16 + l16] =
                f2bf(o[dt][r] * inv);
    }
}

// ---------------------------------------------------------------- launch
extern "C" void kernel_launch(void* const* d_in, const int* in_sizes, int n_in,
                              void* d_out, int out_size, void* d_ws, size_t ws_size,
                              hipStream_t stream) {
    const float* x  = (const float*)d_in[0];
    const float* Wq = (const float*)d_in[1];
    const float* bq = (const float*)d_in[2];
    const float* Wk = (const float*)d_in[3];
    const float* bk = (const float*)d_in[4];
    const float* Wv = (const float*)d_in[5];
    const float* bv = (const float*)d_in[6];
    const float* Wo = (const float*)d_in[7];
    const float* bo = (const float*)d_in[8];
    float* out = (float*)d_out;                    // fp32 output

    const size_t M4 = 4194304, M1 = 1048576;
    const size_t NEED = (M4 + M4 + 3 * M1 + M1) * 2;   // 24 MB
    if (ws_size < NEED) return;
    unsigned short* ws = (unsigned short*)d_ws;
    unsigned short* xb  = ws;                      // 8 MB (dead after QKV gemm)
    unsigned short* Ob  = ws;                      //   ... then Ob (attn output)
    unsigned short* Vt  = ws + M4;                 // 8 MB, [(b*16+h)*64+d][t]
    unsigned short* WtQ = ws + 2 * M4;             // 6 MB: Wq^T,Wk^T,Wv^T stacked
    unsigned short* Wto = WtQ + 3 * M1;            // 2 MB: Wo^T
    unsigned short* Qb  = (unsigned short*)d_out;  // 8 MB scratch in d_out
    unsigned short* Kb  = Qb + M4;                 // 8 MB scratch in d_out

    k_convert_x<<<2048, 256, 0, stream>>>(x, xb);
    k_transpose_w4<<<dim3(16, 16, 4), 256, 0, stream>>>(
        Wq, Wk, Wv, Wo, WtQ, WtQ + M1, WtQ + 2 * M1, Wto);
    k_gemm2<0><<<dim3(32, 24), 256, 0, stream>>>(xb, WtQ, bq, bk, bv,
                                                 Qb, Kb, Vt, nullptr);
    k_attn<<<1024, 256, 0, stream>>>(Qb, Kb, Vt, Ob);
    k_gemm2<1><<<dim3(32, 8), 256, 0, stream>>>(Ob, Wto, bo, nullptr, nullptr,
                                                nullptr, nullptr, nullptr, out);
}